// Round 9
// baseline (502.529 us; speedup 1.0000x reference)
//
#include <hip/hip_runtime.h>
#include <hip/hip_bf16.h>

typedef unsigned short u16;
typedef short bf16x8 __attribute__((ext_vector_type(8)));   // 8 bf16 in 4 VGPRs
typedef float f32x4 __attribute__((ext_vector_type(4)));

#define NN 400
#define NB 10
#define NC 1000
#define CFD 24
#define NFD 85
#define NFROW 86
#define SEDIM 4
#define OEDIM 32
#define XND 121   // 85 + 4 + 32
#define EE 800
#define N_SHAPE_GUARD 7
#define NCHUNK 3125
#define MG_GRID 625   // 5 chunks per block exactly

// bf16 bit helpers (exact load; RNE store)
__device__ __forceinline__ float b2f(u16 u) { return __uint_as_float((unsigned)u << 16); }
__device__ __forceinline__ u16 f2b(float v) {
  unsigned x = __float_as_uint(v);
  return (u16)((x + 0x7fff + ((x >> 16) & 1)) >> 16);
}
__device__ __forceinline__ unsigned pk2(float a, float b) {
  return (unsigned)f2b(a) | ((unsigned)f2b(b) << 16);
}
// runtime-dtype INPUT load: fz=1 -> fp32 buffers, fz=0 -> bf16 buffers
__device__ __forceinline__ float ldf(const void* p, int idx, int fz) {
  if (fz) return ((const float*)p)[idx];
  return b2f(((const u16*)p)[idx]);
}
__device__ __forceinline__ void stf(void* p, int idx, int fz, float v) {
  if (fz) { ((float*)p)[idx] = v; return; }
  ((u16*)p)[idx] = f2b(v);
}

// ---------------- dtype detector: read W1 as bf16; fp32 data -> wild exponents
__global__ void k_detect(const u16* __restrict__ w, int* __restrict__ flag) {
  int t = threadIdx.x;
  int wild = 0;
  for (int j = t; j < 512; j += 64) {
    float a = fabsf(b2f(w[j]));
    if (!(a < 1e4f)) wild++;
  }
  #pragma unroll
  for (int off = 32; off; off >>= 1) wild += __shfl_xor(wild, off);
  if (t == 0) *flag = (wild > 16) ? 1 : 0;   // 1 => inputs are float32
}

// ---------------- prep: A_node = concat(cont, shape_emb, op_emb) @ W1[:121] + b1
__global__ void k_prep(const void* __restrict__ node_feat, const int* __restrict__ opcode,
                       const void* __restrict__ op_emb, const void* __restrict__ shape_emb,
                       const void* __restrict__ W1, const void* __restrict__ b1,
                       const int* __restrict__ dflag, float* __restrict__ A_node) {
  __shared__ float xn[128];
  int fz = *dflag;
  int i = blockIdx.x, t = threadIdx.x;
  float v = 0.f;
  if (t < NFD) {
    v = ldf(node_feat, i*NFROW + t, fz);
  } else if (t < NFD + SEDIM) {
    int st = (int)ldf(node_feat, i*NFROW + NFD, fz);
    st = min(max(st, 0), N_SHAPE_GUARD);
    v = ldf(shape_emb, st*SEDIM + (t - NFD), fz);
  } else if (t < XND) {
    int oc = min(max(opcode[i], 0), 119);
    v = ldf(op_emb, oc*OEDIM + (t - NFD - SEDIM), fz);
  }
  xn[t] = v;
  __syncthreads();
  float acc = ldf(b1, t, fz);
  for (int k = 0; k < XND; k++) acc += xn[k] * ldf(W1, k*128 + t, fz);
  A_node[i*128 + t] = acc;
}

// ---------------- C_cfg = config_feat @ W1[121:145]   (10000 x 128)
__global__ void k_cfg(const void* __restrict__ cfg, const void* __restrict__ W1,
                      const int* __restrict__ dflag, float* __restrict__ C_cfg) {
  int fz = *dflag;
  int r = blockIdx.x, t = threadIdx.x;
  __shared__ float cs[CFD];
  if (t < CFD) cs[t] = ldf(cfg, r*CFD + t, fz);
  __syncthreads();
  float acc = 0.f;
  for (int k = 0; k < CFD; k++) acc += cs[k] * ldf(W1, (XND + k)*128 + t, fz);
  C_cfg[r*128 + t] = acc;
}

// ---------------- pack weights to bf16 TRANSPOSED (n*K+k): MFMA operand layout
__global__ void k_wpackT(const void* __restrict__ W2,
                         const void* __restrict__ Wl0, const void* __restrict__ Wr0,
                         const void* __restrict__ Wl1, const void* __restrict__ Wr1,
                         const void* __restrict__ Wl2, const void* __restrict__ Wr2,
                         const int* __restrict__ dflag,
                         u16* __restrict__ W2t, u16* __restrict__ Wc0t,
                         u16* __restrict__ Wc1t, u16* __restrict__ Wc2t) {
  int fz = *dflag;
  int idx = blockIdx.x * 256 + threadIdx.x;
  if (idx < 16384) {           // W2t[n*128+k] = W2[k*128+n]
    int n = idx >> 7, k = idx & 127;
    W2t[idx] = f2b(ldf(W2, k*128 + n, fz)); return;
  }
  idx -= 16384;
  if (idx < 16384) {           // Wc0t[n*128+k]
    int n = idx >> 7, k = idx & 127;
    float v = (n < 64) ? ldf(Wl0, k*64 + n, fz) : ldf(Wr0, k*64 + n - 64, fz);
    Wc0t[idx] = f2b(v); return;
  }
  idx -= 16384;
  if (idx < 8192) {            // Wc1t[n*64+k]
    int n = idx >> 6, k = idx & 63;
    float v = (n < 64) ? ldf(Wl1, k*64 + n, fz) : ldf(Wr1, k*64 + n - 64, fz);
    Wc1t[idx] = f2b(v); return;
  }
  idx -= 8192;
  if (idx < 8192) {            // Wc2t[n*64+k]
    int n = idx >> 6, k = idx & 63;
    float v = (n < 64) ? ldf(Wl2, k*64 + n, fz) : ldf(Wr2, k*64 + n - 64, fz);
    Wc2t[idx] = f2b(v); return;
  }
}

// ---------------- build CSR (in-edges per dst) + degree
__global__ void k_csr(const int* __restrict__ edge_index, int* __restrict__ offs,
                      int* __restrict__ srcl, float* __restrict__ deg) {
  __shared__ int cnt[NN];
  __shared__ int offl[NN + 1];
  int t = threadIdx.x;
  for (int i = t; i < NN; i += 256) cnt[i] = 0;
  __syncthreads();
  for (int e = t; e < EE; e += 256) {
    int d = edge_index[EE + e] & 511; if (d < NN) atomicAdd(&cnt[d], 1);
  }
  __syncthreads();
  if (t == 0) {
    int s = 0;
    for (int i = 0; i < NN; i++) { offl[i] = s; s += cnt[i]; }
    offl[NN] = s;
  }
  __syncthreads();
  for (int i = t; i < NN; i += 256) { deg[i] = (float)cnt[i]; cnt[i] = offl[i]; }
  for (int i = t; i < NN + 1; i += 256) offs[i] = offl[i];
  __syncthreads();
  for (int e = t; e < EE; e += 256) {
    int d = edge_index[EE + e] & 511;
    if (d < NN) {
      int p = atomicAdd(&cnt[d], 1);
      srcl[p] = min(max(edge_index[e], 0), NN - 1);
    }
  }
}

// ---------------- PERSISTENT MFMA GEMM: Out(M x 128) = Acts(M x K) @ Wt(128 x K)^T
// Weights staged in XOR-swizzled LDS ONCE per block; ONE barrier per kernel;
// then grid-stride over 128-row chunks with register double-buffering of the
// activation fragments (chunk i+1 loads issue before chunk i compute) -> global
// latency overlaps MFMA+stores; waves free-run (no convoy barrier).
// MFMA A = weight frag (m = output ch), B = act frag (n = rows) so D's
// row-axis = output ch -> ushort4 stores.
// In-place safe (In==Out): chunks owned exclusively by one block; prefetch of
// chunk i+gridDim never touches chunk i's rows.
template<int K, bool BUILD, bool BIASRELU>
__global__ __launch_bounds__(256) void k_mgemm(
    const u16* In, const u16* __restrict__ Wt,
    const float* __restrict__ A_node, const float* __restrict__ C_cfg,
    const int* __restrict__ batch,
    const void* __restrict__ bias, const int* __restrict__ dflag, u16* Out) {
  constexpr int KT = K / 32;           // MFMA k-steps
  constexpr int CH = K / 8;            // 16B chunks per weight row
  __shared__ __align__(16) u16 Wlds[128 * K];
  int t = threadIdx.x;
  int w = t >> 6, l = t & 63;
  int lm = l & 15, quad = l >> 4;
  int nrow0 = w * 32;                  // wave's rows within a chunk

  // ---- stage weights (128 x K row-major) into XOR-swizzled LDS, once
  for (int idx = t; idx < 128 * CH; idx += 256) {
    int r = idx / CH, j = idx % CH;
    uint4 v = reinterpret_cast<const uint4*>(Wt)[idx];
    *reinterpret_cast<uint4*>(&Wlds[(r*CH + (j ^ (r & (CH - 1)))) * 8]) = v;
  }
  __syncthreads();                     // the only barrier in this kernel

  auto load_frags = [&](bf16x8 (&dst)[2][KT], int chunk) {
    if (BUILD) {
      #pragma unroll
      for (int nt = 0; nt < 2; nt++) {
        int row = chunk*128 + nrow0 + nt*16 + lm;
        int i = row / NC, c = row - i*NC;
        int b = batch[i] % NB;
        const float* an = A_node + i*128;
        const float* cf = C_cfg + ((size_t)b*NC + c)*128;
        #pragma unroll
        for (int kt = 0; kt < KT; kt++) {
          int ko = kt*32 + quad*8;
          float4 a0 = *(const float4*)(an + ko);
          float4 a1 = *(const float4*)(an + ko + 4);
          float4 c0 = *(const float4*)(cf + ko);
          float4 c1 = *(const float4*)(cf + ko + 4);
          bf16x8 f;
          f[0] = (short)f2b(fmaxf(a0.x + c0.x, 0.f));
          f[1] = (short)f2b(fmaxf(a0.y + c0.y, 0.f));
          f[2] = (short)f2b(fmaxf(a0.z + c0.z, 0.f));
          f[3] = (short)f2b(fmaxf(a0.w + c0.w, 0.f));
          f[4] = (short)f2b(fmaxf(a1.x + c1.x, 0.f));
          f[5] = (short)f2b(fmaxf(a1.y + c1.y, 0.f));
          f[6] = (short)f2b(fmaxf(a1.z + c1.z, 0.f));
          f[7] = (short)f2b(fmaxf(a1.w + c1.w, 0.f));
          dst[nt][kt] = f;
        }
      }
    } else {
      #pragma unroll
      for (int nt = 0; nt < 2; nt++) {
        #pragma unroll
        for (int kt = 0; kt < KT; kt++) {
          int ko = kt*32 + quad*8;
          dst[nt][kt] = *reinterpret_cast<const bf16x8*>(
              In + ((size_t)chunk*128 + nrow0 + nt*16 + lm)*K + ko);
        }
      }
    }
  };

  int fz = 0;
  if (BIASRELU) fz = *dflag;

  bf16x8 cur[2][KT], nxt[2][KT];
  load_frags(cur, blockIdx.x);

  for (int ch_i = blockIdx.x; ch_i < NCHUNK; ch_i += MG_GRID) {
    int ch_n = ch_i + MG_GRID;
    if (ch_n < NCHUNK) load_frags(nxt, ch_n);   // overlaps compute below

    f32x4 acc[8][2] = {};
    #pragma unroll
    for (int kt = 0; kt < KT; kt++) {
      #pragma unroll
      for (int mt = 0; mt < 8; mt++) {
        int oc = mt*16 + lm;
        int ch = (kt*4 + quad) ^ (oc & (CH - 1));
        bf16x8 a = *reinterpret_cast<const bf16x8*>(&Wlds[(oc*CH + ch) * 8]);
        acc[mt][0] = __builtin_amdgcn_mfma_f32_16x16x32_bf16(a, cur[0][kt], acc[mt][0], 0, 0, 0);
        acc[mt][1] = __builtin_amdgcn_mfma_f32_16x16x32_bf16(a, cur[1][kt], acc[mt][1], 0, 0, 0);
      }
    }

    size_t rb = (size_t)ch_i * 128;
    #pragma unroll
    for (int mt = 0; mt < 8; mt++) {
      float bv[4] = {0.f, 0.f, 0.f, 0.f};
      if (BIASRELU) {
        #pragma unroll
        for (int rg = 0; rg < 4; rg++) bv[rg] = ldf(bias, mt*16 + quad*4 + rg, fz);
      }
      #pragma unroll
      for (int nt = 0; nt < 2; nt++) {
        size_t arow = rb + nrow0 + nt*16 + lm;
        ushort4 s;
        float v0 = acc[mt][nt][0], v1 = acc[mt][nt][1];
        float v2 = acc[mt][nt][2], v3 = acc[mt][nt][3];
        if (BIASRELU) {
          v0 = fmaxf(v0 + bv[0], 0.f); v1 = fmaxf(v1 + bv[1], 0.f);
          v2 = fmaxf(v2 + bv[2], 0.f); v3 = fmaxf(v3 + bv[3], 0.f);
        }
        s.x = f2b(v0); s.y = f2b(v1); s.z = f2b(v2); s.w = f2b(v3);
        *reinterpret_cast<ushort4*>(Out + arow*128 + mt*16 + quad*4) = s;
      }
    }

    #pragma unroll
    for (int nt = 0; nt < 2; nt++)
      #pragma unroll
      for (int kt = 0; kt < KT; kt++) cur[nt][kt] = nxt[nt][kt];
  }
}

// ---------------- SAGE combine, vectorized: thread = (row, 8-channel octet)
// x_next = relu(y + (sum_z over in-edges)/max(deg,1) + bg); uint4 loads/stores
__global__ __launch_bounds__(256) void k_agg(
    const u16* __restrict__ yz, const int* __restrict__ offs, const int* __restrict__ srcl,
    const float* __restrict__ deg, const void* __restrict__ bg,
    const int* __restrict__ dflag, u16* __restrict__ xout) {
  int fz = *dflag;
  int g = blockIdx.x * 256 + threadIdx.x;    // 3.2M = 400k rows x 8 octets
  int o = g & 7;
  int row = g >> 3;
  int i = row / NC, c = row - i*NC;
  const uint4* yzv = reinterpret_cast<const uint4*>(yz);
  int o0 = offs[i], o1 = offs[i + 1];
  float a[8] = {0,0,0,0,0,0,0,0};
  for (int e = o0; e < o1; e++) {
    int s = srcl[e];
    uint4 zv = yzv[(size_t)(s*NC + c)*16 + 8 + o];
    a[0] += b2f((u16)(zv.x & 0xffff)); a[1] += b2f((u16)(zv.x >> 16));
    a[2] += b2f((u16)(zv.y & 0xffff)); a[3] += b2f((u16)(zv.y >> 16));
    a[4] += b2f((u16)(zv.z & 0xffff)); a[5] += b2f((u16)(zv.z >> 16));
    a[6] += b2f((u16)(zv.w & 0xffff)); a[7] += b2f((u16)(zv.w >> 16));
  }
  float rd = 1.f / fmaxf(deg[i], 1.f);
  uint4 yv = yzv[(size_t)row*16 + o];
  float y[8];
  y[0] = b2f((u16)(yv.x & 0xffff)); y[1] = b2f((u16)(yv.x >> 16));
  y[2] = b2f((u16)(yv.y & 0xffff)); y[3] = b2f((u16)(yv.y >> 16));
  y[4] = b2f((u16)(yv.z & 0xffff)); y[5] = b2f((u16)(yv.z >> 16));
  y[6] = b2f((u16)(yv.w & 0xffff)); y[7] = b2f((u16)(yv.w >> 16));
  float r[8];
  #pragma unroll
  for (int j = 0; j < 8; j++)
    r[j] = fmaxf(y[j] + a[j]*rd + ldf(bg, o*8 + j, fz), 0.f);
  uint4 s;
  s.x = pk2(r[0], r[1]); s.y = pk2(r[2], r[3]);
  s.z = pk2(r[4], r[5]); s.w = pk2(r[6], r[7]);
  reinterpret_cast<uint4*>(xout)[(size_t)row*8 + o] = s;
}

// ---------------- pool (max + mean over 40 nodes) -> L2 norm -> MLP head
__global__ __launch_bounds__(256) void k_pool(
    const u16* __restrict__ x, const void* __restrict__ Wp1, const void* __restrict__ bp1,
    const void* __restrict__ Wp2, const void* __restrict__ bp2,
    const int* __restrict__ dflag, void* __restrict__ out) {
  int fz = *dflag;
  int b = blockIdx.x / (NC/4);
  int cb = blockIdx.x % (NC/4);
  int t = threadIdx.x;
  int h = t & 63;
  int w = t >> 6;                 // one wave = one config
  int c = cb*4 + w;
  __shared__ float wp1[64*32];
  __shared__ float bp1s[32], wp2s[32];
  __shared__ float xs[4][64];
  for (int f = t; f < 2048; f += 256) wp1[f] = ldf(Wp1, f, fz);
  if (t < 32) { bp1s[t] = ldf(bp1, t, fz); wp2s[t] = ldf(Wp2, t, fz); }
  float mx = -3.0e38f, sm = 0.f;
  for (int j = 0; j < 40; j++) {
    float v = b2f(x[((size_t)(b*40 + j)*NC + c)*64 + h]);
    mx = fmaxf(mx, v); sm += v;
  }
  float g = mx + sm * (1.f / 40.f);
  float sq = g * g;
  #pragma unroll
  for (int off = 32; off; off >>= 1) sq += __shfl_xor(sq, off);
  float gn = g * rsqrtf(sq);
  xs[w][h] = gn;
  __syncthreads();
  int j32 = h & 31;
  float hj = bp1s[j32];
  const float* xr = xs[w];
  for (int k = 0; k < 64; k++) hj += xr[k] * wp1[k*32 + j32];
  hj = fmaxf(hj, 0.f);
  float contrib = hj * wp2s[j32];   // lanes 0-31 and 32-63 duplicate -> sum/2
  #pragma unroll
  for (int off = 32; off; off >>= 1) contrib += __shfl_xor(contrib, off);
  if (h == 0) stf(out, b*NC + c, fz, contrib * 0.5f + ldf(bp2, 0, fz));
}

extern "C" void kernel_launch(void* const* d_in, const int* in_sizes, int n_in,
                              void* d_out, int out_size, void* d_ws, size_t ws_size,
                              hipStream_t stream) {
  const void* node_feat   = d_in[0];
  const int*  node_opcode = (const int*)d_in[1];
  const void* config_feat = d_in[2];
  const int*  edge_index  = (const int*)d_in[3];
  const int*  batch       = (const int*)d_in[4];
  const void* op_emb      = d_in[5];
  const void* shape_emb   = d_in[6];
  const void* W1  = d_in[7];
  const void* b1  = d_in[8];
  const void* W2  = d_in[9];
  const void* b2  = d_in[10];
  const void* Wl0 = d_in[11];
  const void* Wr0 = d_in[12];
  const void* bg0 = d_in[13];
  const void* Wl1 = d_in[14];
  const void* Wr1 = d_in[15];
  const void* bg1 = d_in[16];
  const void* Wl2 = d_in[17];
  const void* Wr2 = d_in[18];
  const void* bg2 = d_in[19];
  const void* Wp1 = d_in[20];
  const void* bp1 = d_in[21];
  const void* Wp2 = d_in[22];
  const void* bp2 = d_in[23];

  // workspace ~159 MB (known-safe; 313 MB faulted in round 2)
  char* p = (char*)d_ws;
  int*   flag   = (int*)p;   p += 256;
  float* A_node = (float*)p; p += 400*128*4;
  float* C_cfg  = (float*)p; p += 10000*128*4;
  u16*   W2t    = (u16*)p;   p += 128*128*2;
  u16*   Wc0t   = (u16*)p;   p += 128*128*2;
  u16*   Wc1t   = (u16*)p;   p += 128*64*2;
  u16*   Wc2t   = (u16*)p;   p += 128*64*2;
  int*   offs   = (int*)p;   p += 2048;
  int*   srcl   = (int*)p;   p += 4096;
  float* deg    = (float*)p; p += 2048;
  u16*   BIG    = (u16*)p;   p += (size_t)400*1000*128*2;   // X2/[y|z] (in-place), bf16
  u16*   X      = (u16*)p;   p += (size_t)400*1000*64*2;    // sage outputs, bf16

  k_detect<<<dim3(1), dim3(64), 0, stream>>>((const u16*)W1, flag);
  k_prep<<<dim3(400), dim3(128), 0, stream>>>(node_feat, node_opcode, op_emb, shape_emb, W1, b1, flag, A_node);
  k_cfg<<<dim3(10000), dim3(128), 0, stream>>>(config_feat, W1, flag, C_cfg);
  k_wpackT<<<dim3(192), dim3(256), 0, stream>>>(W2, Wl0, Wr0, Wl1, Wr1, Wl2, Wr2, flag, W2t, Wc0t, Wc1t, Wc2t);
  k_csr<<<dim3(1), dim3(256), 0, stream>>>(edge_index, offs, srcl, deg);

  // X2 = relu(relu(A_node + C_cfg[batch]) @ W2 + b2)      -> BIG  (fused build)
  k_mgemm<128, true, true><<<dim3(MG_GRID), dim3(256), 0, stream>>>(nullptr, W2t, A_node, C_cfg, batch, b2, flag, BIG);
  // sage0: [y|z] = X2 @ [Wl0|Wr0]                         -> BIG (in-place)
  k_mgemm<128, false, false><<<dim3(MG_GRID), dim3(256), 0, stream>>>(BIG, Wc0t, nullptr, nullptr, nullptr, nullptr, flag, BIG);
  k_agg<<<dim3(12500), dim3(256), 0, stream>>>(BIG, offs, srcl, deg, bg0, flag, X);
  // sage1
  k_mgemm<64, false, false><<<dim3(MG_GRID), dim3(256), 0, stream>>>(X, Wc1t, nullptr, nullptr, nullptr, nullptr, flag, BIG);
  k_agg<<<dim3(12500), dim3(256), 0, stream>>>(BIG, offs, srcl, deg, bg1, flag, X);
  // sage2
  k_mgemm<64, false, false><<<dim3(MG_GRID), dim3(256), 0, stream>>>(X, Wc2t, nullptr, nullptr, nullptr, nullptr, flag, BIG);
  k_agg<<<dim3(12500), dim3(256), 0, stream>>>(BIG, offs, srcl, deg, bg2, flag, X);
  // pool + norm + head
  k_pool<<<dim3(2500), dim3(256), 0, stream>>>(X, Wp1, bp1, Wp2, bp2, flag, d_out);
}

// Round 10
// 456.826 us; speedup vs baseline: 1.1000x; 1.1000x over previous
//
#include <hip/hip_runtime.h>
#include <hip/hip_bf16.h>

typedef unsigned short u16;
typedef short bf16x8 __attribute__((ext_vector_type(8)));   // 8 bf16 in 4 VGPRs
typedef float f32x4 __attribute__((ext_vector_type(4)));

#define NN 400
#define NB 10
#define NC 1000
#define CFD 24
#define NFD 85
#define NFROW 86
#define SEDIM 4
#define OEDIM 32
#define XND 121   // 85 + 4 + 32
#define EE 800
#define N_SHAPE_GUARD 7

// bf16 bit helpers (exact load; RNE store)
__device__ __forceinline__ float b2f(u16 u) { return __uint_as_float((unsigned)u << 16); }
__device__ __forceinline__ u16 f2b(float v) {
  unsigned x = __float_as_uint(v);
  return (u16)((x + 0x7fff + ((x >> 16) & 1)) >> 16);
}
__device__ __forceinline__ unsigned pk2(float a, float b) {
  return (unsigned)f2b(a) | ((unsigned)f2b(b) << 16);
}
// runtime-dtype INPUT load: fz=1 -> fp32 buffers, fz=0 -> bf16 buffers
__device__ __forceinline__ float ldf(const void* p, int idx, int fz) {
  if (fz) return ((const float*)p)[idx];
  return b2f(((const u16*)p)[idx]);
}
__device__ __forceinline__ void stf(void* p, int idx, int fz, float v) {
  if (fz) { ((float*)p)[idx] = v; return; }
  ((u16*)p)[idx] = f2b(v);
}

// ---------------- dtype detector: read W1 as bf16; fp32 data -> wild exponents
__global__ void k_detect(const u16* __restrict__ w, int* __restrict__ flag) {
  int t = threadIdx.x;
  int wild = 0;
  for (int j = t; j < 512; j += 64) {
    float a = fabsf(b2f(w[j]));
    if (!(a < 1e4f)) wild++;
  }
  #pragma unroll
  for (int off = 32; off; off >>= 1) wild += __shfl_xor(wild, off);
  if (t == 0) *flag = (wild > 16) ? 1 : 0;   // 1 => inputs are float32
}

// ---------------- prep: A_node = concat(cont, shape_emb, op_emb) @ W1[:121] + b1
__global__ void k_prep(const void* __restrict__ node_feat, const int* __restrict__ opcode,
                       const void* __restrict__ op_emb, const void* __restrict__ shape_emb,
                       const void* __restrict__ W1, const void* __restrict__ b1,
                       const int* __restrict__ dflag, float* __restrict__ A_node) {
  __shared__ float xn[128];
  int fz = *dflag;
  int i = blockIdx.x, t = threadIdx.x;
  float v = 0.f;
  if (t < NFD) {
    v = ldf(node_feat, i*NFROW + t, fz);
  } else if (t < NFD + SEDIM) {
    int st = (int)ldf(node_feat, i*NFROW + NFD, fz);
    st = min(max(st, 0), N_SHAPE_GUARD);
    v = ldf(shape_emb, st*SEDIM + (t - NFD), fz);
  } else if (t < XND) {
    int oc = min(max(opcode[i], 0), 119);
    v = ldf(op_emb, oc*OEDIM + (t - NFD - SEDIM), fz);
  }
  xn[t] = v;
  __syncthreads();
  float acc = ldf(b1, t, fz);
  for (int k = 0; k < XND; k++) acc += xn[k] * ldf(W1, k*128 + t, fz);
  A_node[i*128 + t] = acc;
}

// ---------------- C_cfg = config_feat @ W1[121:145]   (10000 x 128)
__global__ void k_cfg(const void* __restrict__ cfg, const void* __restrict__ W1,
                      const int* __restrict__ dflag, float* __restrict__ C_cfg) {
  int fz = *dflag;
  int r = blockIdx.x, t = threadIdx.x;
  __shared__ float cs[CFD];
  if (t < CFD) cs[t] = ldf(cfg, r*CFD + t, fz);
  __syncthreads();
  float acc = 0.f;
  for (int k = 0; k < CFD; k++) acc += cs[k] * ldf(W1, (XND + k)*128 + t, fz);
  C_cfg[r*128 + t] = acc;
}

// ---------------- pack weights to bf16 TRANSPOSED (n*K+k): MFMA operand layout
__global__ void k_wpackT(const void* __restrict__ W2,
                         const void* __restrict__ Wl0, const void* __restrict__ Wr0,
                         const void* __restrict__ Wl1, const void* __restrict__ Wr1,
                         const void* __restrict__ Wl2, const void* __restrict__ Wr2,
                         const int* __restrict__ dflag,
                         u16* __restrict__ W2t, u16* __restrict__ Wc0t,
                         u16* __restrict__ Wc1t, u16* __restrict__ Wc2t) {
  int fz = *dflag;
  int idx = blockIdx.x * 256 + threadIdx.x;
  if (idx < 16384) {           // W2t[n*128+k] = W2[k*128+n]
    int n = idx >> 7, k = idx & 127;
    W2t[idx] = f2b(ldf(W2, k*128 + n, fz)); return;
  }
  idx -= 16384;
  if (idx < 16384) {           // Wc0t[n*128+k]
    int n = idx >> 7, k = idx & 127;
    float v = (n < 64) ? ldf(Wl0, k*64 + n, fz) : ldf(Wr0, k*64 + n - 64, fz);
    Wc0t[idx] = f2b(v); return;
  }
  idx -= 16384;
  if (idx < 8192) {            // Wc1t[n*64+k]
    int n = idx >> 6, k = idx & 63;
    float v = (n < 64) ? ldf(Wl1, k*64 + n, fz) : ldf(Wr1, k*64 + n - 64, fz);
    Wc1t[idx] = f2b(v); return;
  }
  idx -= 8192;
  if (idx < 8192) {            // Wc2t[n*64+k]
    int n = idx >> 6, k = idx & 63;
    float v = (n < 64) ? ldf(Wl2, k*64 + n, fz) : ldf(Wr2, k*64 + n - 64, fz);
    Wc2t[idx] = f2b(v); return;
  }
}

// ---------------- build CSR (in-edges per dst) + degree
__global__ void k_csr(const int* __restrict__ edge_index, int* __restrict__ offs,
                      int* __restrict__ srcl, float* __restrict__ deg) {
  __shared__ int cnt[NN];
  __shared__ int offl[NN + 1];
  int t = threadIdx.x;
  for (int i = t; i < NN; i += 256) cnt[i] = 0;
  __syncthreads();
  for (int e = t; e < EE; e += 256) {
    int d = edge_index[EE + e] & 511; if (d < NN) atomicAdd(&cnt[d], 1);
  }
  __syncthreads();
  if (t == 0) {
    int s = 0;
    for (int i = 0; i < NN; i++) { offl[i] = s; s += cnt[i]; }
    offl[NN] = s;
  }
  __syncthreads();
  for (int i = t; i < NN; i += 256) { deg[i] = (float)cnt[i]; cnt[i] = offl[i]; }
  for (int i = t; i < NN + 1; i += 256) offs[i] = offl[i];
  __syncthreads();
  for (int e = t; e < EE; e += 256) {
    int d = edge_index[EE + e] & 511;
    if (d < NN) {
      int p = atomicAdd(&cnt[d], 1);
      srcl[p] = min(max(edge_index[e], 0), NN - 1);
    }
  }
}

// ---------------- MFMA GEMM (r8 core + transposed-store epilogue)
// Out(M x 128) = Acts(M x K) @ Wt(128 x K)^T, bf16, fp32 acc.
// MFMA A = weight frag (m = 128 output ch), B = act frag (n = rows).
// Weights in XOR-swizzled LDS (proven 0 conflicts, r8). Act frags prefetched
// to VGPRs before the single barrier.
// EPILOGUE FIX (r8 store diagnosis): D's lane axis = act-row -> naive stores
// are 256B-strided (64 lines/instr). Route acc through wave-private LDS
// scratch (swizzled transpose), read back row-major -> 8x global_store_dwordx4
// per wave, fully coalesced (16 lines/instr) = 8x fewer store transactions.
// In-place safe (In==Out): block reads only its own 128 rows; reads complete
// (MFMA data-dep) before stores.
template<int K, bool BUILD, bool BIASRELU>
__global__ __launch_bounds__(256) void k_mgemm(
    const u16* In, const u16* __restrict__ Wt,
    const float* __restrict__ A_node, const float* __restrict__ C_cfg,
    const int* __restrict__ batch,
    const void* __restrict__ bias, const int* __restrict__ dflag, u16* Out) {
  constexpr int KT = K / 32;           // MFMA k-steps
  constexpr int CH = K / 8;            // 16B chunks per weight row
  __shared__ __align__(16) u16 Wlds[128 * K + 4 * 2048];   // weights + 4x4KB scratch
  int t = threadIdx.x;
  int w = t >> 6, l = t & 63;
  int lm = l & 15, quad = l >> 4;
  size_t rb = (size_t)blockIdx.x * 128;   // block's first row
  int nrow0 = w * 32;                     // wave's rows within block

  // ---- B-frags (activations), 2 n-tiles x KT, into registers (before barrier)
  bf16x8 bfr[2][KT];
  if (BUILD) {
    #pragma unroll
    for (int nt = 0; nt < 2; nt++) {
      int row = (int)rb + nrow0 + nt*16 + lm;
      int i = row / NC, c = row - i*NC;
      int b = batch[i] % NB;
      const float* an = A_node + i*128;
      const float* cf = C_cfg + ((size_t)b*NC + c)*128;
      #pragma unroll
      for (int kt = 0; kt < KT; kt++) {
        int ko = kt*32 + quad*8;
        float4 a0 = *(const float4*)(an + ko);
        float4 a1 = *(const float4*)(an + ko + 4);
        float4 c0 = *(const float4*)(cf + ko);
        float4 c1 = *(const float4*)(cf + ko + 4);
        bf16x8 f;
        f[0] = (short)f2b(fmaxf(a0.x + c0.x, 0.f));
        f[1] = (short)f2b(fmaxf(a0.y + c0.y, 0.f));
        f[2] = (short)f2b(fmaxf(a0.z + c0.z, 0.f));
        f[3] = (short)f2b(fmaxf(a0.w + c0.w, 0.f));
        f[4] = (short)f2b(fmaxf(a1.x + c1.x, 0.f));
        f[5] = (short)f2b(fmaxf(a1.y + c1.y, 0.f));
        f[6] = (short)f2b(fmaxf(a1.z + c1.z, 0.f));
        f[7] = (short)f2b(fmaxf(a1.w + c1.w, 0.f));
        bfr[nt][kt] = f;
      }
    }
  } else {
    #pragma unroll
    for (int nt = 0; nt < 2; nt++) {
      #pragma unroll
      for (int kt = 0; kt < KT; kt++) {
        int ko = kt*32 + quad*8;
        bfr[nt][kt] = *reinterpret_cast<const bf16x8*>(In + (rb + nrow0 + nt*16 + lm)*K + ko);
      }
    }
  }

  // ---- stage weights (128 x K row-major) into XOR-swizzled LDS
  for (int idx = t; idx < 128 * CH; idx += 256) {
    int r = idx / CH, j = idx % CH;
    uint4 v = reinterpret_cast<const uint4*>(Wt)[idx];
    *reinterpret_cast<uint4*>(&Wlds[(r*CH + (j ^ (r & (CH - 1)))) * 8]) = v;
  }
  __syncthreads();

  // ---- K-loop: swizzled ds_read A-frags (weights) + MFMA
  f32x4 acc[8][2] = {};
  #pragma unroll
  for (int kt = 0; kt < KT; kt++) {
    #pragma unroll
    for (int mt = 0; mt < 8; mt++) {
      int oc = mt*16 + lm;
      int ch = (kt*4 + quad) ^ (oc & (CH - 1));
      bf16x8 a = *reinterpret_cast<const bf16x8*>(&Wlds[(oc*CH + ch) * 8]);
      acc[mt][0] = __builtin_amdgcn_mfma_f32_16x16x32_bf16(a, bfr[0][kt], acc[mt][0], 0, 0, 0);
      acc[mt][1] = __builtin_amdgcn_mfma_f32_16x16x32_bf16(a, bfr[1][kt], acc[mt][1], 0, 0, 0);
    }
  }

  // ---- transposed-store epilogue via wave-private swizzled scratch
  int fz = 0;
  if (BIASRELU) fz = *dflag;
  u16* scr = &Wlds[128 * K + w * 2048];   // 32 rows x 64 cols u16 per wave
  #pragma unroll
  for (int half = 0; half < 2; half++) {
    // write: 8x ds_write_b64, chunk-swizzled (cc ^= (row&7)<<1)
    #pragma unroll
    for (int mt2 = 0; mt2 < 4; mt2++) {
      int mt = half*4 + mt2;
      float bv[4] = {0.f, 0.f, 0.f, 0.f};
      if (BIASRELU) {
        #pragma unroll
        for (int rg = 0; rg < 4; rg++) bv[rg] = ldf(bias, mt*16 + quad*4 + rg, fz);
      }
      #pragma unroll
      for (int nt = 0; nt < 2; nt++) {
        int row32 = nt*16 + lm;
        int cc = mt2*4 + quad;                 // 8B chunk within 64-col row
        int cs = cc ^ ((row32 & 7) << 1);
        ushort4 s;
        float v0 = acc[mt][nt][0], v1 = acc[mt][nt][1];
        float v2 = acc[mt][nt][2], v3 = acc[mt][nt][3];
        if (BIASRELU) {
          v0 = fmaxf(v0 + bv[0], 0.f); v1 = fmaxf(v1 + bv[1], 0.f);
          v2 = fmaxf(v2 + bv[2], 0.f); v3 = fmaxf(v3 + bv[3], 0.f);
        }
        s.x = f2b(v0); s.y = f2b(v1); s.z = f2b(v2); s.w = f2b(v3);
        *reinterpret_cast<ushort4*>(&scr[row32*64 + cs*4]) = s;
      }
    }
    // read back row-major (conflict-free b128) + coalesced 16B/lane stores
    #pragma unroll
    for (int i = 0; i < 4; i++) {
      int row32 = i*8 + (l >> 3);
      int lane8 = l & 7;
      int cs = (lane8*2) ^ ((row32 & 7) << 1);   // even -> pair-adjacent
      uint4 v = *reinterpret_cast<const uint4*>(&scr[row32*64 + cs*4]);
      size_t arow = rb + nrow0 + row32;
      *reinterpret_cast<uint4*>(Out + arow*128 + half*64 + lane8*8) = v;
    }
  }
}

// ---------------- SAGE combine, vectorized: thread = (row, 8-channel octet)
// x_next = relu(y + (sum_z over in-edges)/max(deg,1) + bg); uint4 loads/stores
__global__ __launch_bounds__(256) void k_agg(
    const u16* __restrict__ yz, const int* __restrict__ offs, const int* __restrict__ srcl,
    const float* __restrict__ deg, const void* __restrict__ bg,
    const int* __restrict__ dflag, u16* __restrict__ xout) {
  int fz = *dflag;
  int g = blockIdx.x * 256 + threadIdx.x;    // 3.2M = 400k rows x 8 octets
  int o = g & 7;
  int row = g >> 3;
  int i = row / NC, c = row - i*NC;
  const uint4* yzv = reinterpret_cast<const uint4*>(yz);
  int o0 = offs[i], o1 = offs[i + 1];
  float a[8] = {0,0,0,0,0,0,0,0};
  for (int e = o0; e < o1; e++) {
    int s = srcl[e];
    uint4 zv = yzv[(size_t)(s*NC + c)*16 + 8 + o];
    a[0] += b2f((u16)(zv.x & 0xffff)); a[1] += b2f((u16)(zv.x >> 16));
    a[2] += b2f((u16)(zv.y & 0xffff)); a[3] += b2f((u16)(zv.y >> 16));
    a[4] += b2f((u16)(zv.z & 0xffff)); a[5] += b2f((u16)(zv.z >> 16));
    a[6] += b2f((u16)(zv.w & 0xffff)); a[7] += b2f((u16)(zv.w >> 16));
  }
  float rd = 1.f / fmaxf(deg[i], 1.f);
  uint4 yv = yzv[(size_t)row*16 + o];
  float y[8];
  y[0] = b2f((u16)(yv.x & 0xffff)); y[1] = b2f((u16)(yv.x >> 16));
  y[2] = b2f((u16)(yv.y & 0xffff)); y[3] = b2f((u16)(yv.y >> 16));
  y[4] = b2f((u16)(yv.z & 0xffff)); y[5] = b2f((u16)(yv.z >> 16));
  y[6] = b2f((u16)(yv.w & 0xffff)); y[7] = b2f((u16)(yv.w >> 16));
  float r[8];
  #pragma unroll
  for (int j = 0; j < 8; j++)
    r[j] = fmaxf(y[j] + a[j]*rd + ldf(bg, o*8 + j, fz), 0.f);
  uint4 s;
  s.x = pk2(r[0], r[1]); s.y = pk2(r[2], r[3]);
  s.z = pk2(r[4], r[5]); s.w = pk2(r[6], r[7]);
  reinterpret_cast<uint4*>(xout)[(size_t)row*8 + o] = s;
}

// ---------------- pool (max + mean over 40 nodes) -> L2 norm -> MLP head
__global__ __launch_bounds__(256) void k_pool(
    const u16* __restrict__ x, const void* __restrict__ Wp1, const void* __restrict__ bp1,
    const void* __restrict__ Wp2, const void* __restrict__ bp2,
    const int* __restrict__ dflag, void* __restrict__ out) {
  int fz = *dflag;
  int b = blockIdx.x / (NC/4);
  int cb = blockIdx.x % (NC/4);
  int t = threadIdx.x;
  int h = t & 63;
  int w = t >> 6;                 // one wave = one config
  int c = cb*4 + w;
  __shared__ float wp1[64*32];
  __shared__ float bp1s[32], wp2s[32];
  __shared__ float xs[4][64];
  for (int f = t; f < 2048; f += 256) wp1[f] = ldf(Wp1, f, fz);
  if (t < 32) { bp1s[t] = ldf(bp1, t, fz); wp2s[t] = ldf(Wp2, t, fz); }
  float mx = -3.0e38f, sm = 0.f;
  for (int j = 0; j < 40; j++) {
    float v = b2f(x[((size_t)(b*40 + j)*NC + c)*64 + h]);
    mx = fmaxf(mx, v); sm += v;
  }
  float g = mx + sm * (1.f / 40.f);
  float sq = g * g;
  #pragma unroll
  for (int off = 32; off; off >>= 1) sq += __shfl_xor(sq, off);
  float gn = g * rsqrtf(sq);
  xs[w][h] = gn;
  __syncthreads();
  int j32 = h & 31;
  float hj = bp1s[j32];
  const float* xr = xs[w];
  for (int k = 0; k < 64; k++) hj += xr[k] * wp1[k*32 + j32];
  hj = fmaxf(hj, 0.f);
  float contrib = hj * wp2s[j32];   // lanes 0-31 and 32-63 duplicate -> sum/2
  #pragma unroll
  for (int off = 32; off; off >>= 1) contrib += __shfl_xor(contrib, off);
  if (h == 0) stf(out, b*NC + c, fz, contrib * 0.5f + ldf(bp2, 0, fz));
}

extern "C" void kernel_launch(void* const* d_in, const int* in_sizes, int n_in,
                              void* d_out, int out_size, void* d_ws, size_t ws_size,
                              hipStream_t stream) {
  const void* node_feat   = d_in[0];
  const int*  node_opcode = (const int*)d_in[1];
  const void* config_feat = d_in[2];
  const int*  edge_index  = (const int*)d_in[3];
  const int*  batch       = (const int*)d_in[4];
  const void* op_emb      = d_in[5];
  const void* shape_emb   = d_in[6];
  const void* W1  = d_in[7];
  const void* b1  = d_in[8];
  const void* W2  = d_in[9];
  const void* b2  = d_in[10];
  const void* Wl0 = d_in[11];
  const void* Wr0 = d_in[12];
  const void* bg0 = d_in[13];
  const void* Wl1 = d_in[14];
  const void* Wr1 = d_in[15];
  const void* bg1 = d_in[16];
  const void* Wl2 = d_in[17];
  const void* Wr2 = d_in[18];
  const void* bg2 = d_in[19];
  const void* Wp1 = d_in[20];
  const void* bp1 = d_in[21];
  const void* Wp2 = d_in[22];
  const void* bp2 = d_in[23];

  // workspace ~159 MB (known-safe; 313 MB faulted in round 2)
  char* p = (char*)d_ws;
  int*   flag   = (int*)p;   p += 256;
  float* A_node = (float*)p; p += 400*128*4;
  float* C_cfg  = (float*)p; p += 10000*128*4;
  u16*   W2t    = (u16*)p;   p += 128*128*2;
  u16*   Wc0t   = (u16*)p;   p += 128*128*2;
  u16*   Wc1t   = (u16*)p;   p += 128*64*2;
  u16*   Wc2t   = (u16*)p;   p += 128*64*2;
  int*   offs   = (int*)p;   p += 2048;
  int*   srcl   = (int*)p;   p += 4096;
  float* deg    = (float*)p; p += 2048;
  u16*   BIG    = (u16*)p;   p += (size_t)400*1000*128*2;   // X2/[y|z] (in-place), bf16
  u16*   X      = (u16*)p;   p += (size_t)400*1000*64*2;    // sage outputs, bf16

  k_detect<<<dim3(1), dim3(64), 0, stream>>>((const u16*)W1, flag);
  k_prep<<<dim3(400), dim3(128), 0, stream>>>(node_feat, node_opcode, op_emb, shape_emb, W1, b1, flag, A_node);
  k_cfg<<<dim3(10000), dim3(128), 0, stream>>>(config_feat, W1, flag, C_cfg);
  k_wpackT<<<dim3(192), dim3(256), 0, stream>>>(W2, Wl0, Wr0, Wl1, Wr1, Wl2, Wr2, flag, W2t, Wc0t, Wc1t, Wc2t);
  k_csr<<<dim3(1), dim3(256), 0, stream>>>(edge_index, offs, srcl, deg);

  // X2 = relu(relu(A_node + C_cfg[batch]) @ W2 + b2)      -> BIG  (fused build)
  k_mgemm<128, true, true><<<dim3(3125), dim3(256), 0, stream>>>(nullptr, W2t, A_node, C_cfg, batch, b2, flag, BIG);
  // sage0: [y|z] = X2 @ [Wl0|Wr0]                         -> BIG (in-place)
  k_mgemm<128, false, false><<<dim3(3125), dim3(256), 0, stream>>>(BIG, Wc0t, nullptr, nullptr, nullptr, nullptr, flag, BIG);
  k_agg<<<dim3(12500), dim3(256), 0, stream>>>(BIG, offs, srcl, deg, bg0, flag, X);
  // sage1
  k_mgemm<64, false, false><<<dim3(3125), dim3(256), 0, stream>>>(X, Wc1t, nullptr, nullptr, nullptr, nullptr, flag, BIG);
  k_agg<<<dim3(12500), dim3(256), 0, stream>>>(BIG, offs, srcl, deg, bg1, flag, X);
  // sage2
  k_mgemm<64, false, false><<<dim3(3125), dim3(256), 0, stream>>>(X, Wc2t, nullptr, nullptr, nullptr, nullptr, flag, BIG);
  k_agg<<<dim3(12500), dim3(256), 0, stream>>>(BIG, offs, srcl, deg, bg2, flag, X);
  // pool + norm + head
  k_pool<<<dim3(2500), dim3(256), 0, stream>>>(X, Wp1, bp1, Wp2, bp2, flag, d_out);
}

// Round 11
// 434.697 us; speedup vs baseline: 1.1560x; 1.0509x over previous
//
#include <hip/hip_runtime.h>
#include <hip/hip_bf16.h>

typedef unsigned short u16;
typedef short bf16x8 __attribute__((ext_vector_type(8)));   // 8 bf16 in 4 VGPRs
typedef float f32x4 __attribute__((ext_vector_type(4)));

#define NN 400
#define NB 10
#define NC 1000
#define CFD 24
#define NFD 85
#define NFROW 86
#define SEDIM 4
#define OEDIM 32
#define XND 121   // 85 + 4 + 32
#define EE 800
#define N_SHAPE_GUARD 7

// bf16 bit helpers (exact load; RNE store)
__device__ __forceinline__ float b2f(u16 u) { return __uint_as_float((unsigned)u << 16); }
__device__ __forceinline__ u16 f2b(float v) {
  unsigned x = __float_as_uint(v);
  return (u16)((x + 0x7fff + ((x >> 16) & 1)) >> 16);
}
// runtime-dtype INPUT load: fz=1 -> fp32 buffers, fz=0 -> bf16 buffers
__device__ __forceinline__ float ldf(const void* p, int idx, int fz) {
  if (fz) return ((const float*)p)[idx];
  return b2f(((const u16*)p)[idx]);
}
__device__ __forceinline__ void stf(void* p, int idx, int fz, float v) {
  if (fz) { ((float*)p)[idx] = v; return; }
  ((u16*)p)[idx] = f2b(v);
}

// ---------------- dtype detector: read W1 as bf16; fp32 data -> wild exponents
__global__ void k_detect(const u16* __restrict__ w, int* __restrict__ flag) {
  int t = threadIdx.x;
  int wild = 0;
  for (int j = t; j < 512; j += 64) {
    float a = fabsf(b2f(w[j]));
    if (!(a < 1e4f)) wild++;
  }
  #pragma unroll
  for (int off = 32; off; off >>= 1) wild += __shfl_xor(wild, off);
  if (t == 0) *flag = (wild > 16) ? 1 : 0;   // 1 => inputs are float32
}

// ---------------- prep: A_node = concat(cont, shape_emb, op_emb) @ W1[:121] + b1
__global__ void k_prep(const void* __restrict__ node_feat, const int* __restrict__ opcode,
                       const void* __restrict__ op_emb, const void* __restrict__ shape_emb,
                       const void* __restrict__ W1, const void* __restrict__ b1,
                       const int* __restrict__ dflag, float* __restrict__ A_node) {
  __shared__ float xn[128];
  int fz = *dflag;
  int i = blockIdx.x, t = threadIdx.x;
  float v = 0.f;
  if (t < NFD) {
    v = ldf(node_feat, i*NFROW + t, fz);
  } else if (t < NFD + SEDIM) {
    int st = (int)ldf(node_feat, i*NFROW + NFD, fz);
    st = min(max(st, 0), N_SHAPE_GUARD);
    v = ldf(shape_emb, st*SEDIM + (t - NFD), fz);
  } else if (t < XND) {
    int oc = min(max(opcode[i], 0), 119);
    v = ldf(op_emb, oc*OEDIM + (t - NFD - SEDIM), fz);
  }
  xn[t] = v;
  __syncthreads();
  float acc = ldf(b1, t, fz);
  for (int k = 0; k < XND; k++) acc += xn[k] * ldf(W1, k*128 + t, fz);
  A_node[i*128 + t] = acc;
}

// ---------------- C_cfg = config_feat @ W1[121:145]   (10000 x 128)
__global__ void k_cfg(const void* __restrict__ cfg, const void* __restrict__ W1,
                      const int* __restrict__ dflag, float* __restrict__ C_cfg) {
  int fz = *dflag;
  int r = blockIdx.x, t = threadIdx.x;
  __shared__ float cs[CFD];
  if (t < CFD) cs[t] = ldf(cfg, r*CFD + t, fz);
  __syncthreads();
  float acc = 0.f;
  for (int k = 0; k < CFD; k++) acc += cs[k] * ldf(W1, (XND + k)*128 + t, fz);
  C_cfg[r*128 + t] = acc;
}

// ---------------- pack weights to bf16 TRANSPOSED (n*K+k): MFMA A-operand layout
__global__ void k_wpackT(const void* __restrict__ W2,
                         const void* __restrict__ Wl0, const void* __restrict__ Wr0,
                         const void* __restrict__ Wl1, const void* __restrict__ Wr1,
                         const void* __restrict__ Wl2, const void* __restrict__ Wr2,
                         const int* __restrict__ dflag,
                         u16* __restrict__ W2t, u16* __restrict__ Wc0t,
                         u16* __restrict__ Wc1t, u16* __restrict__ Wc2t) {
  int fz = *dflag;
  int idx = blockIdx.x * 256 + threadIdx.x;
  if (idx < 16384) {           // W2t[n*128+k] = W2[k*128+n]
    int n = idx >> 7, k = idx & 127;
    W2t[idx] = f2b(ldf(W2, k*128 + n, fz)); return;
  }
  idx -= 16384;
  if (idx < 16384) {           // Wc0t[n*128+k]: n<64 -> Wl0, else Wr0
    int n = idx >> 7, k = idx & 127;
    float v = (n < 64) ? ldf(Wl0, k*64 + n, fz) : ldf(Wr0, k*64 + n - 64, fz);
    Wc0t[idx] = f2b(v); return;
  }
  idx -= 16384;
  if (idx < 8192) {            // Wc1t[n*64+k]
    int n = idx >> 6, k = idx & 63;
    float v = (n < 64) ? ldf(Wl1, k*64 + n, fz) : ldf(Wr1, k*64 + n - 64, fz);
    Wc1t[idx] = f2b(v); return;
  }
  idx -= 8192;
  if (idx < 8192) {            // Wc2t[n*64+k]
    int n = idx >> 6, k = idx & 63;
    float v = (n < 64) ? ldf(Wl2, k*64 + n, fz) : ldf(Wr2, k*64 + n - 64, fz);
    Wc2t[idx] = f2b(v); return;
  }
}

// ---------------- build CSR (in-edges per dst)
__global__ void k_csr(const int* __restrict__ edge_index, int* __restrict__ offs,
                      int* __restrict__ srcl) {
  __shared__ int cnt[NN];
  __shared__ int offl[NN + 1];
  int t = threadIdx.x;
  for (int i = t; i < NN; i += 256) cnt[i] = 0;
  __syncthreads();
  for (int e = t; e < EE; e += 256) {
    int d = edge_index[EE + e] & 511; if (d < NN) atomicAdd(&cnt[d], 1);
  }
  __syncthreads();
  if (t == 0) {
    int s = 0;
    for (int i = 0; i < NN; i++) { offl[i] = s; s += cnt[i]; }
    offl[NN] = s;
  }
  __syncthreads();
  for (int i = t; i < NN; i += 256) cnt[i] = offl[i];
  for (int i = t; i < NN + 1; i += 256) offs[i] = offl[i];
  __syncthreads();
  for (int e = t; e < EE; e += 256) {
    int d = edge_index[EE + e] & 511;
    if (d < NN) {
      int p = atomicAdd(&cnt[d], 1);
      srcl[p] = min(max(edge_index[e], 0), NN - 1);
    }
  }
}

// ---------------- FUSED per-config pipeline (TileEarlyJoin):
// block = one config c. All activations live in LDS; weights live in VGPRs
// (LDS caps us at 1 block/CU -> 512 VGPRs/wave available).
// P1: x2 = relu(relu(A_node+C_cfg[b,c])@W2+b2)        -> xbuf (400x128)
// P2: x3 = relu(x2@Wl0 + mean_in(x2)@Wr0 + bg0)       -> ybuf (400x64)
// P3: x4 = relu(x3@Wl1 + mean_in(x3)@Wr1 + bg1)       -> xbuf (400x64 region)
// P4: x5 = relu(x4@Wl2 + mean_in(x4)@Wr2 + bg2)       -> ybuf
// P5: per batch: max+mean pool -> L2 norm -> MLP head  -> out[b*NC+c]
// mean-before-GEMM is exact by linearity of the aggregation.
// LDS layout swizzle: 16B chunk ch' = ch ^ (row & 7) everywhere (reads b128
// land 2 lanes/bank = free). MFMA: A=weights (m=out ch), B=acts (n=rows).
__global__ __launch_bounds__(256, 1) void k_fused(
    const float* __restrict__ A_node, const float* __restrict__ C_cfg,
    const int* __restrict__ batch, const int* __restrict__ offs,
    const int* __restrict__ srcl,
    const u16* __restrict__ W2t, const u16* __restrict__ Wc0t,
    const u16* __restrict__ Wc1t, const u16* __restrict__ Wc2t,
    const void* __restrict__ b2, const void* __restrict__ bg0,
    const void* __restrict__ bg1, const void* __restrict__ bg2,
    const void* __restrict__ Wp1, const void* __restrict__ bp1,
    const void* __restrict__ Wp2, const void* __restrict__ bp2,
    const int* __restrict__ dflag, void* __restrict__ out) {
  __shared__ __align__(16) u16 xbuf[400 * 128];   // 102400 B
  __shared__ __align__(16) u16 ybuf[400 * 64];    //  51200 B
  __shared__ int offsl[401];
  __shared__ int srcll[EE];

  int c = blockIdx.x;
  int t = threadIdx.x;
  int w = t >> 6, l = t & 63;
  int lm = l & 15, quad = l >> 4;
  int fz = *dflag;

  // stage cfg rows (aliased into ybuf; dead after P1) + CSR
  float* cfgl = (float*)ybuf;                    // 10*128 fp32 = 5120 B
  for (int idx = t; idx < 1280; idx += 256)
    cfgl[idx] = C_cfg[((size_t)(idx >> 7) * NC + c) * 128 + (idx & 127)];
  for (int idx = t; idx < 401; idx += 256) offsl[idx] = offs[idx];
  for (int idx = t; idx < EE; idx += 256) srcll[idx] = srcl[idx];
  __syncthreads();

  // ================= P1: build x2 (K=128 -> 128 out) =================
  {
    bf16x8 wf[8][4];
    #pragma unroll
    for (int mt = 0; mt < 8; mt++)
      #pragma unroll
      for (int kt = 0; kt < 4; kt++)
        wf[mt][kt] = *reinterpret_cast<const bf16x8*>(W2t + (mt*16 + lm)*128 + kt*32 + quad*8);
    float bv[8][4];
    #pragma unroll
    for (int mt = 0; mt < 8; mt++)
      #pragma unroll
      for (int rg = 0; rg < 4; rg++) bv[mt][rg] = ldf(b2, mt*16 + quad*4 + rg, fz);

    for (int tile = w; tile < 25; tile += 4) {
      int i = tile*16 + lm;
      int b = batch[i] % NB;
      const float* an = A_node + i*128;
      const float* cf = cfgl + b*128;
      bf16x8 bfr[4];
      #pragma unroll
      for (int kt = 0; kt < 4; kt++) {
        int ko = kt*32 + quad*8;
        float4 a0 = *(const float4*)(an + ko);
        float4 a1 = *(const float4*)(an + ko + 4);
        float4 c0 = *(const float4*)(cf + ko);
        float4 c1 = *(const float4*)(cf + ko + 4);
        bf16x8 f;
        f[0] = (short)f2b(fmaxf(a0.x + c0.x, 0.f));
        f[1] = (short)f2b(fmaxf(a0.y + c0.y, 0.f));
        f[2] = (short)f2b(fmaxf(a0.z + c0.z, 0.f));
        f[3] = (short)f2b(fmaxf(a0.w + c0.w, 0.f));
        f[4] = (short)f2b(fmaxf(a1.x + c1.x, 0.f));
        f[5] = (short)f2b(fmaxf(a1.y + c1.y, 0.f));
        f[6] = (short)f2b(fmaxf(a1.z + c1.z, 0.f));
        f[7] = (short)f2b(fmaxf(a1.w + c1.w, 0.f));
        bfr[kt] = f;
      }
      f32x4 acc[8] = {};
      #pragma unroll
      for (int kt = 0; kt < 4; kt++)
        #pragma unroll
        for (int mt = 0; mt < 8; mt++)
          acc[mt] = __builtin_amdgcn_mfma_f32_16x16x32_bf16(wf[mt][kt], bfr[kt], acc[mt], 0, 0, 0);
      #pragma unroll
      for (int mt = 0; mt < 8; mt++) {
        ushort4 s;
        s.x = f2b(fmaxf(acc[mt][0] + bv[mt][0], 0.f));
        s.y = f2b(fmaxf(acc[mt][1] + bv[mt][1], 0.f));
        s.z = f2b(fmaxf(acc[mt][2] + bv[mt][2], 0.f));
        s.w = f2b(fmaxf(acc[mt][3] + bv[mt][3], 0.f));
        int ch = mt*2 + (quad >> 1);
        int chs = ch ^ (i & 7);
        *reinterpret_cast<ushort4*>(&xbuf[i*128 + chs*8 + (quad & 1)*4]) = s;
      }
    }
  }
  __syncthreads();

  // ================= P2: sage0 (in xbuf 128-wide -> out ybuf 64-wide) =====
  {
    bf16x8 wl[4][4], wr[4][4];
    #pragma unroll
    for (int mt = 0; mt < 4; mt++)
      #pragma unroll
      for (int kt = 0; kt < 4; kt++) {
        wl[mt][kt] = *reinterpret_cast<const bf16x8*>(Wc0t + (mt*16 + lm)*128 + kt*32 + quad*8);
        wr[mt][kt] = *reinterpret_cast<const bf16x8*>(Wc0t + (64 + mt*16 + lm)*128 + kt*32 + quad*8);
      }
    float bv[4][4];
    #pragma unroll
    for (int mt = 0; mt < 4; mt++)
      #pragma unroll
      for (int rg = 0; rg < 4; rg++) bv[mt][rg] = ldf(bg0, mt*16 + quad*4 + rg, fz);

    for (int tile = w; tile < 25; tile += 4) {
      int i = tile*16 + lm;
      int o0 = offsl[i], o1 = offsl[i + 1];
      float rd = 1.f / fmaxf((float)(o1 - o0), 1.f);
      bf16x8 xf[4], mf[4];
      #pragma unroll
      for (int kt = 0; kt < 4; kt++)
        xf[kt] = *reinterpret_cast<const bf16x8*>(&xbuf[i*128 + ((kt*4 + quad) ^ (i & 7))*8]);
      #pragma unroll
      for (int kt = 0; kt < 4; kt++) {
        float s8[8] = {0,0,0,0,0,0,0,0};
        for (int e = o0; e < o1; e++) {
          int sn = srcll[e];
          bf16x8 zv = *reinterpret_cast<const bf16x8*>(&xbuf[sn*128 + ((kt*4 + quad) ^ (sn & 7))*8]);
          #pragma unroll
          for (int j = 0; j < 8; j++) s8[j] += b2f((u16)zv[j]);
        }
        bf16x8 f;
        #pragma unroll
        for (int j = 0; j < 8; j++) f[j] = (short)f2b(s8[j] * rd);
        mf[kt] = f;
      }
      f32x4 acc[4] = {};
      #pragma unroll
      for (int kt = 0; kt < 4; kt++)
        #pragma unroll
        for (int mt = 0; mt < 4; mt++) {
          acc[mt] = __builtin_amdgcn_mfma_f32_16x16x32_bf16(wl[mt][kt], xf[kt], acc[mt], 0, 0, 0);
          acc[mt] = __builtin_amdgcn_mfma_f32_16x16x32_bf16(wr[mt][kt], mf[kt], acc[mt], 0, 0, 0);
        }
      #pragma unroll
      for (int mt = 0; mt < 4; mt++) {
        ushort4 s;
        s.x = f2b(fmaxf(acc[mt][0] + bv[mt][0], 0.f));
        s.y = f2b(fmaxf(acc[mt][1] + bv[mt][1], 0.f));
        s.z = f2b(fmaxf(acc[mt][2] + bv[mt][2], 0.f));
        s.w = f2b(fmaxf(acc[mt][3] + bv[mt][3], 0.f));
        int ch = mt*2 + (quad >> 1);
        int chs = ch ^ (i & 7);
        *reinterpret_cast<ushort4*>(&ybuf[i*64 + chs*8 + (quad & 1)*4]) = s;
      }
    }
  }
  __syncthreads();

  // ================= P3 / P4: sage1, sage2 (64-wide, K=64) =================
  u16* src_buf = ybuf;
  u16* dst_buf = xbuf;          // reuse first 51.2 KB of xbuf
  for (int layer = 0; layer < 2; layer++) {
    const u16* Wt = (layer == 0) ? Wc1t : Wc2t;
    const void* bg = (layer == 0) ? bg1 : bg2;
    bf16x8 wl[4][2], wr[4][2];
    #pragma unroll
    for (int mt = 0; mt < 4; mt++)
      #pragma unroll
      for (int kt = 0; kt < 2; kt++) {
        wl[mt][kt] = *reinterpret_cast<const bf16x8*>(Wt + (mt*16 + lm)*64 + kt*32 + quad*8);
        wr[mt][kt] = *reinterpret_cast<const bf16x8*>(Wt + (64 + mt*16 + lm)*64 + kt*32 + quad*8);
      }
    float bv[4][4];
    #pragma unroll
    for (int mt = 0; mt < 4; mt++)
      #pragma unroll
      for (int rg = 0; rg < 4; rg++) bv[mt][rg] = ldf(bg, mt*16 + quad*4 + rg, fz);

    for (int tile = w; tile < 25; tile += 4) {
      int i = tile*16 + lm;
      int o0 = offsl[i], o1 = offsl[i + 1];
      float rd = 1.f / fmaxf((float)(o1 - o0), 1.f);
      bf16x8 xf[2], mf[2];
      #pragma unroll
      for (int kt = 0; kt < 2; kt++)
        xf[kt] = *reinterpret_cast<const bf16x8*>(&src_buf[i*64 + ((kt*4 + quad) ^ (i & 7))*8]);
      #pragma unroll
      for (int kt = 0; kt < 2; kt++) {
        float s8[8] = {0,0,0,0,0,0,0,0};
        for (int e = o0; e < o1; e++) {
          int sn = srcll[e];
          bf16x8 zv = *reinterpret_cast<const bf16x8*>(&src_buf[sn*64 + ((kt*4 + quad) ^ (sn & 7))*8]);
          #pragma unroll
          for (int j = 0; j < 8; j++) s8[j] += b2f((u16)zv[j]);
        }
        bf16x8 f;
        #pragma unroll
        for (int j = 0; j < 8; j++) f[j] = (short)f2b(s8[j] * rd);
        mf[kt] = f;
      }
      f32x4 acc[4] = {};
      #pragma unroll
      for (int kt = 0; kt < 2; kt++)
        #pragma unroll
        for (int mt = 0; mt < 4; mt++) {
          acc[mt] = __builtin_amdgcn_mfma_f32_16x16x32_bf16(wl[mt][kt], xf[kt], acc[mt], 0, 0, 0);
          acc[mt] = __builtin_amdgcn_mfma_f32_16x16x32_bf16(wr[mt][kt], mf[kt], acc[mt], 0, 0, 0);
        }
      #pragma unroll
      for (int mt = 0; mt < 4; mt++) {
        ushort4 s;
        s.x = f2b(fmaxf(acc[mt][0] + bv[mt][0], 0.f));
        s.y = f2b(fmaxf(acc[mt][1] + bv[mt][1], 0.f));
        s.z = f2b(fmaxf(acc[mt][2] + bv[mt][2], 0.f));
        s.w = f2b(fmaxf(acc[mt][3] + bv[mt][3], 0.f));
        int ch = mt*2 + (quad >> 1);
        int chs = ch ^ (i & 7);
        *reinterpret_cast<ushort4*>(&dst_buf[i*64 + chs*8 + (quad & 1)*4]) = s;
      }
    }
    __syncthreads();
    u16* tmp = src_buf; src_buf = dst_buf; dst_buf = tmp;
  }
  // after 2 layers: x5 is in ybuf (src_buf == ybuf)

  // ================= P5: pool + L2 norm + MLP head =================
  {
    float* scr = (float*)xbuf;            // free; per-wave region scr[w*64+..]
    for (int b = w; b < NB; b += 4) {
      int h = l;
      float mx = -3.0e38f, sm = 0.f;
      for (int j = 0; j < 40; j++) {
        int row = b*40 + j;
        int chs = (h >> 3) ^ (row & 7);
        float v = b2f(src_buf[row*64 + chs*8 + (h & 7)]);
        mx = fmaxf(mx, v); sm += v;
      }
      float g = mx + sm * (1.f / 40.f);
      float sq = g * g;
      #pragma unroll
      for (int off = 32; off; off >>= 1) sq += __shfl_xor(sq, off);
      float gn = g * rsqrtf(sq);
      scr[w*64 + h] = gn;
      int j32 = l & 31;
      float hj = ldf(bp1, j32, fz);
      for (int k = 0; k < 64; k++) hj += scr[w*64 + k] * ldf(Wp1, k*32 + j32, fz);
      hj = fmaxf(hj, 0.f);
      float contrib = hj * ldf(Wp2, j32, fz);   // halves duplicate -> x0.5
      #pragma unroll
      for (int off = 32; off; off >>= 1) contrib += __shfl_xor(contrib, off);
      if (l == 0) stf(out, b*NC + c, fz, contrib * 0.5f + ldf(bp2, 0, fz));
    }
  }
}

extern "C" void kernel_launch(void* const* d_in, const int* in_sizes, int n_in,
                              void* d_out, int out_size, void* d_ws, size_t ws_size,
                              hipStream_t stream) {
  const void* node_feat   = d_in[0];
  const int*  node_opcode = (const int*)d_in[1];
  const void* config_feat = d_in[2];
  const int*  edge_index  = (const int*)d_in[3];
  const int*  batch       = (const int*)d_in[4];
  const void* op_emb      = d_in[5];
  const void* shape_emb   = d_in[6];
  const void* W1  = d_in[7];
  const void* b1  = d_in[8];
  const void* W2  = d_in[9];
  const void* b2  = d_in[10];
  const void* Wl0 = d_in[11];
  const void* Wr0 = d_in[12];
  const void* bg0 = d_in[13];
  const void* Wl1 = d_in[14];
  const void* Wr1 = d_in[15];
  const void* bg1 = d_in[16];
  const void* Wl2 = d_in[17];
  const void* Wr2 = d_in[18];
  const void* bg2 = d_in[19];
  const void* Wp1 = d_in[20];
  const void* bp1 = d_in[21];
  const void* Wp2 = d_in[22];
  const void* bp2 = d_in[23];

  // workspace ~5.6 MB (down from 159 MB: all big intermediates now in LDS)
  char* p = (char*)d_ws;
  int*   flag   = (int*)p;   p += 256;
  float* A_node = (float*)p; p += 400*128*4;
  float* C_cfg  = (float*)p; p += 10000*128*4;
  u16*   W2t    = (u16*)p;   p += 128*128*2;
  u16*   Wc0t   = (u16*)p;   p += 128*128*2;
  u16*   Wc1t   = (u16*)p;   p += 128*64*2;
  u16*   Wc2t   = (u16*)p;   p += 128*64*2;
  int*   offs   = (int*)p;   p += 2048;
  int*   srcl   = (int*)p;   p += 4096;

  k_detect<<<dim3(1), dim3(64), 0, stream>>>((const u16*)W1, flag);
  k_prep<<<dim3(400), dim3(128), 0, stream>>>(node_feat, node_opcode, op_emb, shape_emb, W1, b1, flag, A_node);
  k_cfg<<<dim3(10000), dim3(128), 0, stream>>>(config_feat, W1, flag, C_cfg);
  k_wpackT<<<dim3(192), dim3(256), 0, stream>>>(W2, Wl0, Wr0, Wl1, Wr1, Wl2, Wr2, flag, W2t, Wc0t, Wc1t, Wc2t);
  k_csr<<<dim3(1), dim3(256), 0, stream>>>(edge_index, offs, srcl);

  k_fused<<<dim3(1000), dim3(256), 0, stream>>>(
      A_node, C_cfg, batch, offs, srcl, W2t, Wc0t, Wc1t, Wc2t,
      b2, bg0, bg1, bg2, Wp1, bp1, Wp2, bp2, flag, d_out);
}

// Round 12
// 336.889 us; speedup vs baseline: 1.4917x; 1.2903x over previous
//
#include <hip/hip_runtime.h>
#include <hip/hip_bf16.h>

typedef unsigned short u16;
typedef short bf16x8 __attribute__((ext_vector_type(8)));   // 8 bf16 in 4 VGPRs
typedef float f32x4 __attribute__((ext_vector_type(4)));

#define NN 400
#define NB 10
#define NC 1000
#define CFD 24
#define NFD 85
#define NFROW 86
#define SEDIM 4
#define OEDIM 32
#define XND 121   // 85 + 4 + 32
#define EE 800
#define N_SHAPE_GUARD 7

// bf16 bit helpers (exact load; RNE store)
__device__ __forceinline__ float b2f(u16 u) { return __uint_as_float((unsigned)u << 16); }
__device__ __forceinline__ u16 f2b(float v) {
  unsigned x = __float_as_uint(v);
  return (u16)((x + 0x7fff + ((x >> 16) & 1)) >> 16);
}
// runtime-dtype INPUT load: fz=1 -> fp32 buffers, fz=0 -> bf16 buffers
__device__ __forceinline__ float ldf(const void* p, int idx, int fz) {
  if (fz) return ((const float*)p)[idx];
  return b2f(((const u16*)p)[idx]);
}
__device__ __forceinline__ void stf(void* p, int idx, int fz, float v) {
  if (fz) { ((float*)p)[idx] = v; return; }
  ((u16*)p)[idx] = f2b(v);
}

// ---------------- dtype detector: read W1 as bf16; fp32 data -> wild exponents
__global__ void k_detect(const u16* __restrict__ w, int* __restrict__ flag) {
  int t = threadIdx.x;
  int wild = 0;
  for (int j = t; j < 512; j += 64) {
    float a = fabsf(b2f(w[j]));
    if (!(a < 1e4f)) wild++;
  }
  #pragma unroll
  for (int off = 32; off; off >>= 1) wild += __shfl_xor(wild, off);
  if (t == 0) *flag = (wild > 16) ? 1 : 0;   // 1 => inputs are float32
}

// ---------------- prep: A_node = concat(cont, shape_emb, op_emb) @ W1[:121] + b1
__global__ void k_prep(const void* __restrict__ node_feat, const int* __restrict__ opcode,
                       const void* __restrict__ op_emb, const void* __restrict__ shape_emb,
                       const void* __restrict__ W1, const void* __restrict__ b1,
                       const int* __restrict__ dflag, float* __restrict__ A_node) {
  __shared__ float xn[128];
  int fz = *dflag;
  int i = blockIdx.x, t = threadIdx.x;
  float v = 0.f;
  if (t < NFD) {
    v = ldf(node_feat, i*NFROW + t, fz);
  } else if (t < NFD + SEDIM) {
    int st = (int)ldf(node_feat, i*NFROW + NFD, fz);
    st = min(max(st, 0), N_SHAPE_GUARD);
    v = ldf(shape_emb, st*SEDIM + (t - NFD), fz);
  } else if (t < XND) {
    int oc = min(max(opcode[i], 0), 119);
    v = ldf(op_emb, oc*OEDIM + (t - NFD - SEDIM), fz);
  }
  xn[t] = v;
  __syncthreads();
  float acc = ldf(b1, t, fz);
  for (int k = 0; k < XND; k++) acc += xn[k] * ldf(W1, k*128 + t, fz);
  A_node[i*128 + t] = acc;
}

// ---------------- C_cfg = config_feat @ W1[121:145]   (10000 x 128)
__global__ void k_cfg(const void* __restrict__ cfg, const void* __restrict__ W1,
                      const int* __restrict__ dflag, float* __restrict__ C_cfg) {
  int fz = *dflag;
  int r = blockIdx.x, t = threadIdx.x;
  __shared__ float cs[CFD];
  if (t < CFD) cs[t] = ldf(cfg, r*CFD + t, fz);
  __syncthreads();
  float acc = 0.f;
  for (int k = 0; k < CFD; k++) acc += cs[k] * ldf(W1, (XND + k)*128 + t, fz);
  C_cfg[r*128 + t] = acc;
}

// ---------------- pack weights to bf16 TRANSPOSED (n*K+k): MFMA A-operand layout
__global__ void k_wpackT(const void* __restrict__ W2,
                         const void* __restrict__ Wl0, const void* __restrict__ Wr0,
                         const void* __restrict__ Wl1, const void* __restrict__ Wr1,
                         const void* __restrict__ Wl2, const void* __restrict__ Wr2,
                         const int* __restrict__ dflag,
                         u16* __restrict__ W2t, u16* __restrict__ Wc0t,
                         u16* __restrict__ Wc1t, u16* __restrict__ Wc2t) {
  int fz = *dflag;
  int idx = blockIdx.x * 256 + threadIdx.x;
  if (idx < 16384) {           // W2t[n*128+k] = W2[k*128+n]
    int n = idx >> 7, k = idx & 127;
    W2t[idx] = f2b(ldf(W2, k*128 + n, fz)); return;
  }
  idx -= 16384;
  if (idx < 16384) {           // Wc0t[n*128+k]: n<64 -> Wl0, else Wr0
    int n = idx >> 7, k = idx & 127;
    float v = (n < 64) ? ldf(Wl0, k*64 + n, fz) : ldf(Wr0, k*64 + n - 64, fz);
    Wc0t[idx] = f2b(v); return;
  }
  idx -= 16384;
  if (idx < 8192) {            // Wc1t[n*64+k]
    int n = idx >> 6, k = idx & 63;
    float v = (n < 64) ? ldf(Wl1, k*64 + n, fz) : ldf(Wr1, k*64 + n - 64, fz);
    Wc1t[idx] = f2b(v); return;
  }
  idx -= 8192;
  if (idx < 8192) {            // Wc2t[n*64+k]
    int n = idx >> 6, k = idx & 63;
    float v = (n < 64) ? ldf(Wl2, k*64 + n, fz) : ldf(Wr2, k*64 + n - 64, fz);
    Wc2t[idx] = f2b(v); return;
  }
}

// ---------------- build CSR (in-edges per dst)
__global__ void k_csr(const int* __restrict__ edge_index, int* __restrict__ offs,
                      int* __restrict__ srcl) {
  __shared__ int cnt[NN];
  __shared__ int offl[NN + 1];
  int t = threadIdx.x;
  for (int i = t; i < NN; i += 256) cnt[i] = 0;
  __syncthreads();
  for (int e = t; e < EE; e += 256) {
    int d = edge_index[EE + e] & 511; if (d < NN) atomicAdd(&cnt[d], 1);
  }
  __syncthreads();
  if (t == 0) {
    int s = 0;
    for (int i = 0; i < NN; i++) { offl[i] = s; s += cnt[i]; }
    offl[NN] = s;
  }
  __syncthreads();
  for (int i = t; i < NN; i += 256) cnt[i] = offl[i];
  for (int i = t; i < NN + 1; i += 256) offs[i] = offl[i];
  __syncthreads();
  for (int e = t; e < EE; e += 256) {
    int d = edge_index[EE + e] & 511;
    if (d < NN) {
      int p = atomicAdd(&cnt[d], 1);
      srcl[p] = min(max(edge_index[e], 0), NN - 1);
    }
  }
}

// ---------------- FUSED per-config pipeline, 512 threads (8 waves):
// block = one config. All activations in LDS; weights in VGPRs.
// r11 post-mortem: 4 waves couldn't hide ds_read latency (70% idle) and the
// edge-gather was a serial chain (srcl -> addr -> read -> add per edge per kt).
// Fixes: 8 waves/CU; edge-major gather w/ 2-edge unroll (8 reads in flight);
// Wp1 staged in LDS for the head.
__global__ __launch_bounds__(512, 1) void k_fused(
    const float* __restrict__ A_node, const float* __restrict__ C_cfg,
    const int* __restrict__ batch, const int* __restrict__ offs,
    const int* __restrict__ srcl,
    const u16* __restrict__ W2t, const u16* __restrict__ Wc0t,
    const u16* __restrict__ Wc1t, const u16* __restrict__ Wc2t,
    const void* __restrict__ b2, const void* __restrict__ bg0,
    const void* __restrict__ bg1, const void* __restrict__ bg2,
    const void* __restrict__ Wp1, const void* __restrict__ bp1,
    const void* __restrict__ Wp2, const void* __restrict__ bp2,
    const int* __restrict__ dflag, void* __restrict__ out) {
  __shared__ __align__(16) u16 xbuf[400 * 128];   // 102400 B
  __shared__ __align__(16) u16 ybuf[400 * 64];    //  51200 B
  __shared__ int offsl[401];
  __shared__ int srcll[EE];

  int c = blockIdx.x;
  int t = threadIdx.x;
  int w = t >> 6, l = t & 63;       // 8 waves
  int lm = l & 15, quad = l >> 4;
  int fz = *dflag;

  // stage cfg rows (aliased into ybuf; dead after P1) + CSR
  float* cfgl = (float*)ybuf;                    // 10*128 fp32 = 5120 B
  for (int idx = t; idx < 1280; idx += 512)
    cfgl[idx] = C_cfg[((size_t)(idx >> 7) * NC + c) * 128 + (idx & 127)];
  for (int idx = t; idx < 401; idx += 512) offsl[idx] = offs[idx];
  for (int idx = t; idx < EE; idx += 512) srcll[idx] = srcl[idx];
  __syncthreads();

  // ================= P1: build x2 (K=128 -> 128 out) =================
  {
    bf16x8 wf[8][4];
    #pragma unroll
    for (int mt = 0; mt < 8; mt++)
      #pragma unroll
      for (int kt = 0; kt < 4; kt++)
        wf[mt][kt] = *reinterpret_cast<const bf16x8*>(W2t + (mt*16 + lm)*128 + kt*32 + quad*8);
    float bv[8][4];
    #pragma unroll
    for (int mt = 0; mt < 8; mt++)
      #pragma unroll
      for (int rg = 0; rg < 4; rg++) bv[mt][rg] = ldf(b2, mt*16 + quad*4 + rg, fz);

    for (int tile = w; tile < 25; tile += 8) {
      int i = tile*16 + lm;
      int b = batch[i] % NB;
      const float* an = A_node + i*128;
      const float* cf = cfgl + b*128;
      bf16x8 bfr[4];
      #pragma unroll
      for (int kt = 0; kt < 4; kt++) {
        int ko = kt*32 + quad*8;
        float4 a0 = *(const float4*)(an + ko);
        float4 a1 = *(const float4*)(an + ko + 4);
        float4 c0 = *(const float4*)(cf + ko);
        float4 c1 = *(const float4*)(cf + ko + 4);
        bf16x8 f;
        f[0] = (short)f2b(fmaxf(a0.x + c0.x, 0.f));
        f[1] = (short)f2b(fmaxf(a0.y + c0.y, 0.f));
        f[2] = (short)f2b(fmaxf(a0.z + c0.z, 0.f));
        f[3] = (short)f2b(fmaxf(a0.w + c0.w, 0.f));
        f[4] = (short)f2b(fmaxf(a1.x + c1.x, 0.f));
        f[5] = (short)f2b(fmaxf(a1.y + c1.y, 0.f));
        f[6] = (short)f2b(fmaxf(a1.z + c1.z, 0.f));
        f[7] = (short)f2b(fmaxf(a1.w + c1.w, 0.f));
        bfr[kt] = f;
      }
      f32x4 acc[8] = {};
      #pragma unroll
      for (int kt = 0; kt < 4; kt++)
        #pragma unroll
        for (int mt = 0; mt < 8; mt++)
          acc[mt] = __builtin_amdgcn_mfma_f32_16x16x32_bf16(wf[mt][kt], bfr[kt], acc[mt], 0, 0, 0);
      #pragma unroll
      for (int mt = 0; mt < 8; mt++) {
        ushort4 s;
        s.x = f2b(fmaxf(acc[mt][0] + bv[mt][0], 0.f));
        s.y = f2b(fmaxf(acc[mt][1] + bv[mt][1], 0.f));
        s.z = f2b(fmaxf(acc[mt][2] + bv[mt][2], 0.f));
        s.w = f2b(fmaxf(acc[mt][3] + bv[mt][3], 0.f));
        int ch = mt*2 + (quad >> 1);
        int chs = ch ^ (i & 7);
        *reinterpret_cast<ushort4*>(&xbuf[i*128 + chs*8 + (quad & 1)*4]) = s;
      }
    }
  }
  __syncthreads();

  // ================= P2: sage0 (xbuf 128-wide -> ybuf 64-wide) =====
  {
    bf16x8 wl[4][4], wr[4][4];
    #pragma unroll
    for (int mt = 0; mt < 4; mt++)
      #pragma unroll
      for (int kt = 0; kt < 4; kt++) {
        wl[mt][kt] = *reinterpret_cast<const bf16x8*>(Wc0t + (mt*16 + lm)*128 + kt*32 + quad*8);
        wr[mt][kt] = *reinterpret_cast<const bf16x8*>(Wc0t + (64 + mt*16 + lm)*128 + kt*32 + quad*8);
      }
    float bv[4][4];
    #pragma unroll
    for (int mt = 0; mt < 4; mt++)
      #pragma unroll
      for (int rg = 0; rg < 4; rg++) bv[mt][rg] = ldf(bg0, mt*16 + quad*4 + rg, fz);

    for (int tile = w; tile < 25; tile += 8) {
      int i = tile*16 + lm;
      int o0 = offsl[i], o1 = offsl[i + 1];
      float rd = 1.f / fmaxf((float)(o1 - o0), 1.f);
      bf16x8 xf[4], mf[4];
      #pragma unroll
      for (int kt = 0; kt < 4; kt++)
        xf[kt] = *reinterpret_cast<const bf16x8*>(&xbuf[i*128 + ((kt*4 + quad) ^ (i & 7))*8]);
      // edge-major gather, 2-edge unroll (8 independent ds_reads in flight)
      float s8[4][8] = {};
      int e = o0;
      for (; e + 1 < o1; e += 2) {
        int sn0 = srcll[e], sn1 = srcll[e + 1];
        bf16x8 z0[4], z1[4];
        #pragma unroll
        for (int kt = 0; kt < 4; kt++) {
          z0[kt] = *reinterpret_cast<const bf16x8*>(&xbuf[sn0*128 + ((kt*4 + quad) ^ (sn0 & 7))*8]);
          z1[kt] = *reinterpret_cast<const bf16x8*>(&xbuf[sn1*128 + ((kt*4 + quad) ^ (sn1 & 7))*8]);
        }
        #pragma unroll
        for (int kt = 0; kt < 4; kt++)
          #pragma unroll
          for (int j = 0; j < 8; j++) {
            s8[kt][j] += b2f((u16)z0[kt][j]);
            s8[kt][j] += b2f((u16)z1[kt][j]);
          }
      }
      if (e < o1) {
        int sn0 = srcll[e];
        #pragma unroll
        for (int kt = 0; kt < 4; kt++) {
          bf16x8 zv = *reinterpret_cast<const bf16x8*>(&xbuf[sn0*128 + ((kt*4 + quad) ^ (sn0 & 7))*8]);
          #pragma unroll
          for (int j = 0; j < 8; j++) s8[kt][j] += b2f((u16)zv[j]);
        }
      }
      #pragma unroll
      for (int kt = 0; kt < 4; kt++) {
        bf16x8 f;
        #pragma unroll
        for (int j = 0; j < 8; j++) f[j] = (short)f2b(s8[kt][j] * rd);
        mf[kt] = f;
      }
      f32x4 acc[4] = {};
      #pragma unroll
      for (int kt = 0; kt < 4; kt++)
        #pragma unroll
        for (int mt = 0; mt < 4; mt++) {
          acc[mt] = __builtin_amdgcn_mfma_f32_16x16x32_bf16(wl[mt][kt], xf[kt], acc[mt], 0, 0, 0);
          acc[mt] = __builtin_amdgcn_mfma_f32_16x16x32_bf16(wr[mt][kt], mf[kt], acc[mt], 0, 0, 0);
        }
      #pragma unroll
      for (int mt = 0; mt < 4; mt++) {
        ushort4 s;
        s.x = f2b(fmaxf(acc[mt][0] + bv[mt][0], 0.f));
        s.y = f2b(fmaxf(acc[mt][1] + bv[mt][1], 0.f));
        s.z = f2b(fmaxf(acc[mt][2] + bv[mt][2], 0.f));
        s.w = f2b(fmaxf(acc[mt][3] + bv[mt][3], 0.f));
        int ch = mt*2 + (quad >> 1);
        int chs = ch ^ (i & 7);
        *reinterpret_cast<ushort4*>(&ybuf[i*64 + chs*8 + (quad & 1)*4]) = s;
      }
    }
  }
  __syncthreads();

  // ================= P3 / P4: sage1, sage2 (64-wide, K=64) =================
  u16* src_buf = ybuf;
  u16* dst_buf = xbuf;          // reuse first 51.2 KB of xbuf
  for (int layer = 0; layer < 2; layer++) {
    const u16* Wt = (layer == 0) ? Wc1t : Wc2t;
    const void* bg = (layer == 0) ? bg1 : bg2;
    bf16x8 wl[4][2], wr[4][2];
    #pragma unroll
    for (int mt = 0; mt < 4; mt++)
      #pragma unroll
      for (int kt = 0; kt < 2; kt++) {
        wl[mt][kt] = *reinterpret_cast<const bf16x8*>(Wt + (mt*16 + lm)*64 + kt*32 + quad*8);
        wr[mt][kt] = *reinterpret_cast<const bf16x8*>(Wt + (64 + mt*16 + lm)*64 + kt*32 + quad*8);
      }
    float bv[4][4];
    #pragma unroll
    for (int mt = 0; mt < 4; mt++)
      #pragma unroll
      for (int rg = 0; rg < 4; rg++) bv[mt][rg] = ldf(bg, mt*16 + quad*4 + rg, fz);

    for (int tile = w; tile < 25; tile += 8) {
      int i = tile*16 + lm;
      int o0 = offsl[i], o1 = offsl[i + 1];
      float rd = 1.f / fmaxf((float)(o1 - o0), 1.f);
      bf16x8 xf[2], mf[2];
      #pragma unroll
      for (int kt = 0; kt < 2; kt++)
        xf[kt] = *reinterpret_cast<const bf16x8*>(&src_buf[i*64 + ((kt*4 + quad) ^ (i & 7))*8]);
      float s8[2][8] = {};
      int e = o0;
      for (; e + 1 < o1; e += 2) {
        int sn0 = srcll[e], sn1 = srcll[e + 1];
        bf16x8 z0[2], z1[2];
        #pragma unroll
        for (int kt = 0; kt < 2; kt++) {
          z0[kt] = *reinterpret_cast<const bf16x8*>(&src_buf[sn0*64 + ((kt*4 + quad) ^ (sn0 & 7))*8]);
          z1[kt] = *reinterpret_cast<const bf16x8*>(&src_buf[sn1*64 + ((kt*4 + quad) ^ (sn1 & 7))*8]);
        }
        #pragma unroll
        for (int kt = 0; kt < 2; kt++)
          #pragma unroll
          for (int j = 0; j < 8; j++) {
            s8[kt][j] += b2f((u16)z0[kt][j]);
            s8[kt][j] += b2f((u16)z1[kt][j]);
          }
      }
      if (e < o1) {
        int sn0 = srcll[e];
        #pragma unroll
        for (int kt = 0; kt < 2; kt++) {
          bf16x8 zv = *reinterpret_cast<const bf16x8*>(&src_buf[sn0*64 + ((kt*4 + quad) ^ (sn0 & 7))*8]);
          #pragma unroll
          for (int j = 0; j < 8; j++) s8[kt][j] += b2f((u16)zv[j]);
        }
      }
      #pragma unroll
      for (int kt = 0; kt < 2; kt++) {
        bf16x8 f;
        #pragma unroll
        for (int j = 0; j < 8; j++) f[j] = (short)f2b(s8[kt][j] * rd);
        mf[kt] = f;
      }
      f32x4 acc[4] = {};
      #pragma unroll
      for (int kt = 0; kt < 2; kt++)
        #pragma unroll
        for (int mt = 0; mt < 4; mt++) {
          acc[mt] = __builtin_amdgcn_mfma_f32_16x16x32_bf16(wl[mt][kt], xf[kt], acc[mt], 0, 0, 0);
          acc[mt] = __builtin_amdgcn_mfma_f32_16x16x32_bf16(wr[mt][kt], mf[kt], acc[mt], 0, 0, 0);
        }
      #pragma unroll
      for (int mt = 0; mt < 4; mt++) {
        ushort4 s;
        s.x = f2b(fmaxf(acc[mt][0] + bv[mt][0], 0.f));
        s.y = f2b(fmaxf(acc[mt][1] + bv[mt][1], 0.f));
        s.z = f2b(fmaxf(acc[mt][2] + bv[mt][2], 0.f));
        s.w = f2b(fmaxf(acc[mt][3] + bv[mt][3], 0.f));
        int ch = mt*2 + (quad >> 1);
        int chs = ch ^ (i & 7);
        *reinterpret_cast<ushort4*>(&dst_buf[i*64 + chs*8 + (quad & 1)*4]) = s;
      }
    }
    __syncthreads();
    u16* tmp = src_buf; src_buf = dst_buf; dst_buf = tmp;
  }
  // after 2 layers: x5 is in ybuf (src_buf == ybuf); xbuf region free

  // ================= P5: pool + L2 norm + MLP head =================
  {
    float* scr  = (float*)xbuf;                 // 8 waves x 64 fp32 = 2 KB
    float* wp1s = (float*)&xbuf[4096];          // 2048 fp32 = 8 KB (offset 8 KB)
    for (int idx = t; idx < 2048; idx += 512) wp1s[idx] = ldf(Wp1, idx, fz);
    __syncthreads();
    for (int b = w; b < NB; b += 8) {
      int h = l;
      float mx = -3.0e38f, sm = 0.f;
      for (int j = 0; j < 40; j++) {
        int row = b*40 + j;
        int chs = (h >> 3) ^ (row & 7);
        float v = b2f(src_buf[row*64 + chs*8 + (h & 7)]);
        mx = fmaxf(mx, v); sm += v;
      }
      float g = mx + sm * (1.f / 40.f);
      float sq = g * g;
      #pragma unroll
      for (int off = 32; off; off >>= 1) sq += __shfl_xor(sq, off);
      float gn = g * rsqrtf(sq);
      scr[w*64 + h] = gn;
      int j32 = l & 31;
      float hj = ldf(bp1, j32, fz);
      for (int k = 0; k < 64; k++) hj += scr[w*64 + k] * wp1s[k*32 + j32];
      hj = fmaxf(hj, 0.f);
      float contrib = hj * ldf(Wp2, j32, fz);   // halves duplicate -> x0.5
      #pragma unroll
      for (int off = 32; off; off >>= 1) contrib += __shfl_xor(contrib, off);
      if (l == 0) stf(out, b*NC + c, fz, contrib * 0.5f + ldf(bp2, 0, fz));
    }
  }
}

extern "C" void kernel_launch(void* const* d_in, const int* in_sizes, int n_in,
                              void* d_out, int out_size, void* d_ws, size_t ws_size,
                              hipStream_t stream) {
  const void* node_feat   = d_in[0];
  const int*  node_opcode = (const int*)d_in[1];
  const void* config_feat = d_in[2];
  const int*  edge_index  = (const int*)d_in[3];
  const int*  batch       = (const int*)d_in[4];
  const void* op_emb      = d_in[5];
  const void* shape_emb   = d_in[6];
  const void* W1  = d_in[7];
  const void* b1  = d_in[8];
  const void* W2  = d_in[9];
  const void* b2  = d_in[10];
  const void* Wl0 = d_in[11];
  const void* Wr0 = d_in[12];
  const void* bg0 = d_in[13];
  const void* Wl1 = d_in[14];
  const void* Wr1 = d_in[15];
  const void* bg1 = d_in[16];
  const void* Wl2 = d_in[17];
  const void* Wr2 = d_in[18];
  const void* bg2 = d_in[19];
  const void* Wp1 = d_in[20];
  const void* bp1 = d_in[21];
  const void* Wp2 = d_in[22];
  const void* bp2 = d_in[23];

  // workspace ~5.6 MB (all big intermediates live in LDS)
  char* p = (char*)d_ws;
  int*   flag   = (int*)p;   p += 256;
  float* A_node = (float*)p; p += 400*128*4;
  float* C_cfg  = (float*)p; p += 10000*128*4;
  u16*   W2t    = (u16*)p;   p += 128*128*2;
  u16*   Wc0t   = (u16*)p;   p += 128*128*2;
  u16*   Wc1t   = (u16*)p;   p += 128*64*2;
  u16*   Wc2t   = (u16*)p;   p += 128*64*2;
  int*   offs   = (int*)p;   p += 2048;
  int*   srcl   = (int*)p;   p += 4096;

  k_detect<<<dim3(1), dim3(64), 0, stream>>>((const u16*)W1, flag);
  k_prep<<<dim3(400), dim3(128), 0, stream>>>(node_feat, node_opcode, op_emb, shape_emb, W1, b1, flag, A_node);
  k_cfg<<<dim3(10000), dim3(128), 0, stream>>>(config_feat, W1, flag, C_cfg);
  k_wpackT<<<dim3(192), dim3(256), 0, stream>>>(W2, Wl0, Wr0, Wl1, Wr1, Wl2, Wr2, flag, W2t, Wc0t, Wc1t, Wc2t);
  k_csr<<<dim3(1), dim3(256), 0, stream>>>(edge_index, offs, srcl);

  k_fused<<<dim3(1000), dim3(512), 0, stream>>>(
      A_node, C_cfg, batch, offs, srcl, W2t, Wc0t, Wc1t, Wc2t,
      b2, bg0, bg1, bg2, Wp1, bp1, Wp2, bp2, flag, d_out);
}